// Round 9
// baseline (3130.349 us; speedup 1.0000x reference)
//
#include <hip/hip_runtime.h>
#include <cstdint>
#include <cstddef>

typedef unsigned short u16;
typedef unsigned int u32;
typedef unsigned long long u64;
typedef __attribute__((ext_vector_type(8))) short short8;   // 8 x bf16
typedef __attribute__((ext_vector_type(4))) float f32x4;

#define MFMA16(a, b, c) __builtin_amdgcn_mfma_f32_16x16x32_bf16((a), (b), (c), 0, 0, 0)
#define SCOPE_AGENT __HIP_MEMORY_SCOPE_AGENT

// B=64, T=512, D=512, H=1024.
// R9: eager flag publish. R6 (best, 4.0us/step) paid the h-store ACK (~900cy to the
// coherent point) BEFORE publishing its flag -> ack on the global critical path.
// R9 publishes the per-wave flag immediately after ISSUING the h stores (in-order
// VMEM issue makes flag chase data; the sentinel backstop absorbs flag-first
// arrival). The ack cost moves to the producer's own next gate (first-round
// vmcnt(0) drains own stores) where it overlaps all other WGs' progress. Narrow
// per-wave gate (wave w gates on its 8 producer cgs x 4 waves); safety induction:
// cg X publishing h(t) implies X's 4 waves gated (t-1) over ALL 32 cgs -> everyone
// finished step t-2 -> reset-ahead-4 (buf[(t+4)&7], holding h(t-4)) is never still
// being read. Reset acks ordered by the next step's gate drain. Single lgkm-only
// reduce barrier (red double-buffered). Everything else = R6 proven config: agent
// h/flag stores (write-through; locally L2-visible -> sc0 loads hit L2, FETCH
// 148MB proved it), sc0 loads w/ hwreg-seeded fast mode + sticky bounded-spin
// escalation to agent loads (hang-proof on any topology).

static __device__ __forceinline__ u16 f2bf_rne(float f) {
  uint32_t u = __float_as_uint(f);
  u += 0x7FFFu + ((u >> 16) & 1u);
  return (u16)(u >> 16);
}
static __device__ __forceinline__ float bf2f(u16 h) {
  return __uint_as_float((uint32_t)h << 16);
}

// sentinel 0xFFFF = bf16 NaN; tanh outputs / remainders are finite -> never 0xFFFF.
static __device__ __forceinline__ u32 stale4(int4 d) {
  u32 s = 0;
#pragma unroll
  for (int j = 0; j < 4; ++j) {
    u32 x = ((u32*)&d)[j];
    s |= (u32)((x >> 16) == 0xFFFFu) | (u32)((x & 0xFFFFu) == 0xFFFFu);
  }
  return s;
}

// fast: sc0 load (XCD L2). esc: agent-scope atomic loads (proven-visible pair).
static __device__ __forceinline__ int4 ld16(const u16* p, bool esc) {
  int4 r;
  if (!esc) {
    asm volatile("global_load_dwordx4 %0, %1, off sc0" : "=v"(r) : "v"(p));
  } else {
    u64 a = __hip_atomic_load((const u64*)p, __ATOMIC_RELAXED, SCOPE_AGENT);
    u64 b = __hip_atomic_load(((const u64*)p) + 1, __ATOMIC_RELAXED, SCOPE_AGENT);
    r.x = (int)(u32)a; r.y = (int)(u32)(a >> 32);
    r.z = (int)(u32)b; r.w = (int)(u32)(b >> 32);
  }
  return r;
}
static __device__ __forceinline__ u32 ldF(const u32* p, bool esc) {
  u32 r;
  if (!esc)
    asm volatile("global_load_dword %0, %1, off sc0" : "=v"(r) : "v"(p));
  else
    r = __hip_atomic_load(p, __ATOMIC_RELAXED, SCOPE_AGENT);
  return r;
}
static __device__ __forceinline__ void stH(u16* p, u16 v) {
  __hip_atomic_store(p, v, __ATOMIC_RELAXED, SCOPE_AGENT);
}
static __device__ __forceinline__ void stFlag(u32* p, u32 v) {
  __hip_atomic_store(p, v, __ATOMIC_RELAXED, SCOPE_AGENT);
}

// rule #18: drain vmcnt, then hard scheduling fence.
static __device__ __forceinline__ void waitv0() {
  asm volatile("s_waitcnt vmcnt(0)" ::: "memory");
  __builtin_amdgcn_sched_barrier(0);
}
// LDS-only barrier: vmcnt rides through (in-flight VMEM not stalled).
static __device__ __forceinline__ void bar_lgkm() {
  asm volatile("s_waitcnt lgkmcnt(0)" ::: "memory");
  __builtin_amdgcn_s_barrier();
  __builtin_amdgcn_sched_barrier(0);
}

// ---------------- prep ----------------
__global__ void split_arr(const float* __restrict__ src, u16* __restrict__ hi,
                          u16* __restrict__ lo, int n) {
  int i = blockIdx.x * blockDim.x + threadIdx.x;
  if (i >= n) return;
  float f = src[i];
  u16 h = f2bf_rne(f);
  hi[i] = h;
  lo[i] = f2bf_rne(f - bf2f(h));
}

__global__ void bias_init(const float* __restrict__ a, const float* __restrict__ b,
                          float* __restrict__ o, u32* __restrict__ cnt,
                          u32* __restrict__ flg) {
  int i = blockIdx.x * blockDim.x + threadIdx.x;
  if (i < 1024) o[i] = a[i] + b[i];
  if (i < 1024) __hip_atomic_store(flg + i, 0u, __ATOMIC_RELAXED, SCOPE_AGENT);
  if (i < 8) __hip_atomic_store(cnt + i * 64, 0u, __ATOMIC_RELAXED, SCOPE_AGENT);
}

// ---------------- phase 1: xin = x @ W_in^T + bsum -> d_out (unchanged, proven) ----
__global__ __launch_bounds__(256) void xin_gemm(
    const float* __restrict__ x, const u16* __restrict__ Bh, const u16* __restrict__ Bl,
    const float* __restrict__ bsum, float* __restrict__ out) {
  __shared__ u16 Ahi[64 * 40], Alo[64 * 40], Bhi[64 * 40], Blo[64 * 40];
  const int mb = blockIdx.y * 64, nb = blockIdx.x * 64;
  const int tid = threadIdx.x, wave = tid >> 6, lane = tid & 63;
  const int mn = lane & 15, q = lane >> 4;
  const int srow = tid >> 2, scg = tid & 3;

  f32x4 acc[4] = {};
  for (int kb = 0; kb < 512; kb += 32) {
    const float* ap = x + (size_t)(mb + srow) * 512 + kb + scg * 8;
    float4 a0 = *(const float4*)ap;
    float4 a1 = *(const float4*)(ap + 4);
    float av[8] = {a0.x, a0.y, a0.z, a0.w, a1.x, a1.y, a1.z, a1.w};
    short8 vh, vl;
#pragma unroll
    for (int j = 0; j < 8; ++j) {
      u16 h = f2bf_rne(av[j]);
      vh[j] = (short)h;
      vl[j] = (short)f2bf_rne(av[j] - bf2f(h));
    }
    short8 wh = *(const short8*)(Bh + (size_t)(nb + srow) * 512 + kb + scg * 8);
    short8 wl = *(const short8*)(Bl + (size_t)(nb + srow) * 512 + kb + scg * 8);

    __syncthreads();
    *(short8*)&Ahi[srow * 40 + scg * 8] = vh;
    *(short8*)&Alo[srow * 40 + scg * 8] = vl;
    *(short8*)&Bhi[srow * 40 + scg * 8] = wh;
    *(short8*)&Blo[srow * 40 + scg * 8] = wl;
    __syncthreads();

    short8 ah = *(const short8*)&Ahi[(wave * 16 + mn) * 40 + q * 8];
    short8 al = *(const short8*)&Alo[(wave * 16 + mn) * 40 + q * 8];
#pragma unroll
    for (int nt = 0; nt < 4; ++nt) {
      short8 bh8 = *(const short8*)&Bhi[(nt * 16 + mn) * 40 + q * 8];
      short8 bl8 = *(const short8*)&Blo[(nt * 16 + mn) * 40 + q * 8];
      acc[nt] = MFMA16(ah, bh8, acc[nt]);
      acc[nt] = MFMA16(al, bh8, acc[nt]);
      acc[nt] = MFMA16(ah, bl8, acc[nt]);
    }
  }
#pragma unroll
  for (int nt = 0; nt < 4; ++nt)
#pragma unroll
    for (int r = 0; r < 4; ++r) {
      int row = mb + wave * 16 + q * 4 + r;
      int col = nb + nt * 16 + mn;
      out[(size_t)row * 1024 + col] = acc[nt][r] + bsum[col];
    }
}

// ---------------- phase 2 step loop ----------------
// Per step t: [narrow gate; first round's waitv0 drains OWN prev-step stores
// (ack overlapped with other WGs' progress)] [8 A loads + waitv0] [per-chunk
// sentinel retry] [xin(t+1) prefetch] [reset buf[(t+4)&7]] [8x2x2 MFMA]
// [red write] [lgkm-only barrier] [cross-wave sum] [tanh] [h stores ISSUED]
// [lane0 flag := t+1 ISSUED -- no ack wait] [io store]. In-order VMEM issue makes
// the flag chase the data; flag-first arrival at a consumer is absorbed by its
// sentinel retry. Reset(t) ack is ordered before the t+3 data store by the
// step-(t+1) gate/sentinel waitv0.
static __device__ __forceinline__ void run_steps(
    u16* hhi, u16* hlo, float* __restrict__ io, const u16* Whi, const u16* Wlo,
    float* red, u32* bgflg, int b0, int c0, int cg, int wave, int mn,
    int q, int om, int on, int lane, bool esc) {
  const int kbase = wave * 256;
  u16* aplane = (mn < 8) ? hhi : hlo;  // A rows 0-7 = hi, 8-15 = lo
  const size_t abase = (size_t)(b0 + (mn & 7)) * 1024 + kbase + q * 8;
  const size_t iobase = (size_t)(b0 + om) * 512 * 1024 + (c0 + on);
  const size_t hword = (size_t)(b0 + om) * 1024 + (c0 + on);
  // consumer gate: flags of producer cgs 8w..8w+7 x 4 waves = indices 32w..32w+31
  const u32* fp = bgflg + wave * 32 + (lane & 31);
  u32* myflag = bgflg + cg * 4 + wave;  // my per-wave flag

  // W frags (compiler may keep in VGPR or re-read LDS; both fine)
  short8 bhf[8][2], blf[8][2];
#pragma unroll
  for (int kt = 0; kt < 8; ++kt) {
    const int k = kbase + kt * 32 + q * 8;
#pragma unroll
    for (int nt = 0; nt < 2; ++nt) {
      bhf[kt][nt] = *(const short8*)&Whi[(nt * 16 + mn) * 1032 + k];
      blf[kt][nt] = *(const short8*)&Wlo[(nt * 16 + mn) * 1032 + k];
    }
  }

  float xv = io[iobase];  // xin(0)
  {                       // t = 0: h0 == 0 -> h1 = tanh(xin0), no GEMM
    float o = tanhf(xv);
    u16 hh = f2bf_rne(o);
    stH(hhi + (1u << 16) + hword, hh);
    stH(hlo + (1u << 16) + hword, f2bf_rne(o - bf2f(hh)));
    if (lane == 0) stFlag(myflag, 1u);  // eager publish: flag chases data
    io[iobase] = o;
    xv = io[iobase + 1024];             // xin(1)
  }

  for (int t = 1; t < 512; ++t) {
    const u32 ut = (u32)t;
    // ---- narrow gate; first round drains own prev-step stores ----
    {
      int rounds = 0;
      for (;;) {
        u32 f = ut;
        if (lane < 32) f = ldF(fp, esc);
        waitv0();
        if (__ballot(f >= ut) == ~0ull) break;
        if (!esc && ++rounds >= 1024) esc = true;  // sticky, proven-visible pair
      }
    }

    // ---- A-slice load; per-chunk sentinel retry (flag may precede data) ----
    const u16* pA = aplane + ((size_t)(t & 7) << 16) + abase;
    int4 v[8];
#pragma unroll
    for (int kt = 0; kt < 8; ++kt) v[kt] = ld16(pA + kt * 32, esc);
    waitv0();
    u32 sm = 0;
#pragma unroll
    for (int kt = 0; kt < 8; ++kt) sm |= stale4(v[kt]) << kt;
    {
      int spins = 0;
      while (__builtin_expect(sm != 0, 0)) {
        if (!esc && ++spins >= 256) esc = true;
#pragma unroll
        for (int kt = 0; kt < 8; ++kt)
          if (sm & (1u << kt)) v[kt] = ld16(pA + kt * 32, esc);
        waitv0();
        sm = 0;
#pragma unroll
        for (int kt = 0; kt < 8; ++kt) sm |= stale4(v[kt]) << kt;
      }
    }

    // xin(t+1): HBM latency hides under MFMA/barrier; compiler waits before use.
    float xn = 0.f;
    if (t < 511) xn = io[iobase + (size_t)(t + 1) * 1024];

    if (t < 508) {  // reset buf[(t+4)&7]: holds h(t-4); nobody below step t-1 exists
      const size_t roff = ((size_t)((t + 4) & 7) << 16) + hword;
      stH(hhi + roff, 0xFFFFu);
      stH(hlo + roff, 0xFFFFu);
    }

    f32x4 acc[2] = {};
#pragma unroll
    for (int kt = 0; kt < 8; ++kt) {
      short8 a = *(short8*)&v[kt];
#pragma unroll
      for (int nt = 0; nt < 2; ++nt) {
        acc[nt] = MFMA16(a, bhf[kt][nt], acc[nt]);  // rows 0-7: hi*Whi, 8-15: lo*Whi
        acc[nt] = MFMA16(a, blf[kt][nt], acc[nt]);  // rows 0-7: hi*Wlo, 8-15: lo*Wlo
      }
    }

    float* rp = red + (t & 1) * 2112;
#pragma unroll
    for (int nt = 0; nt < 2; ++nt)
#pragma unroll
      for (int r = 0; r < 4; ++r)
        rp[wave * 528 + (q * 4 + r) * 33 + nt * 16 + mn] = acc[nt][r];
    bar_lgkm();  // LDS drain only; in-flight VMEM rides through

    float s = 0.f;
#pragma unroll
    for (int w = 0; w < 4; ++w)
      s += rp[w * 528 + om * 33 + on] + rp[w * 528 + (om + 8) * 33 + on];
    float o = tanhf(s + xv);

    if (t < 511) {
      u16 hh = f2bf_rne(o);
      const size_t doff = ((size_t)((t + 1) & 7) << 16) + hword;
      stH(hhi + doff, hh);
      stH(hlo + doff, f2bf_rne(o - bf2f(hh)));
      // EAGER publish: no ack wait. In-order issue -> flag follows data into the
      // hierarchy; a consumer seeing flag-before-data retries via sentinels.
      if (lane == 0) stFlag(myflag, ut + 1);
    }
    io[iobase + (size_t)t * 1024] = o;
    xv = xn;
  }
}

// ---------------- phase 2 kernel ----------------
__global__ __launch_bounds__(256, 1) void rnn_steps(
    const u16* __restrict__ Wh, const u16* __restrict__ Wl, u16* hhi, u16* hlo,
    u32* cnt, u32* xccbuf, u32* flg, float* __restrict__ io) {
  extern __shared__ __align__(16) char smem[];
  u16* Whi = (u16*)smem;                 // [32][1032]  66048 B
  u16* Wlo = (u16*)(smem + 66048);       // [32][1032]  66048 B
  float* red = (float*)(smem + 132096);  // [2][4][16][33] 16896 B

  const int tid = threadIdx.x, wave = tid >> 6, lane = tid & 63;
  const int mn = lane & 15, q = lane >> 4;
  const int wgid = blockIdx.x;
  const int bg = wgid & 7, cg = wgid >> 3;
  const int c0 = cg * 32, b0 = bg * 8;
  u32* mycnt = cnt + bg * 64;

  // persistent W tile: 32 cols x 1024, hi+lo
  for (int it = tid; it < 32 * 128; it += 256) {
    int r = it >> 7, c = it & 127;
    *(short8*)&Whi[r * 1032 + c * 8] = *(const short8*)(Wh + (size_t)(c0 + r) * 1024 + c * 8);
    *(short8*)&Wlo[r * 1032 + c * 8] = *(const short8*)(Wl + (size_t)(c0 + r) * 1024 + c * 8);
  }

  // output ownership: 256 threads -> 8 batches x 32 cols, 1 col/thread
  const int om = tid >> 5, on = tid & 31;
  const size_t hword = (size_t)(b0 + om) * 1024 + (c0 + on);

  // sentinel-prefill my word in ALL 8 buffers (agent scope, MALL + local-L2 visible)
#pragma unroll
  for (int bb = 0; bb < 8; ++bb) {
    stH(hhi + ((size_t)bb << 16) + hword, 0xFFFFu);
    stH(hlo + ((size_t)bb << 16) + hword, 0xFFFFu);
  }

  // publish my XCD id (numeric hwreg 20 = XCC_ID, low 4 bits; worked in R5/R6);
  // per-bg startup barrier; verify bg co-residency. Any mis-read is safe:
  // false-negative -> agent path; false-positive -> bounded-spin escalation.
  u32 xcc;
  asm volatile("s_getreg_b32 %0, hwreg(20, 0, 4)" : "=s"(xcc));
  if (tid == 0)
    __hip_atomic_store(xccbuf + wgid, xcc, __ATOMIC_RELAXED, SCOPE_AGENT);
  asm volatile("s_waitcnt vmcnt(0)" ::: "memory");
  __syncthreads();
  if (tid == 0) {
    __hip_atomic_fetch_add(mycnt, 1u, __ATOMIC_RELAXED, SCOPE_AGENT);
    while (__hip_atomic_load(mycnt, __ATOMIC_RELAXED, SCOPE_AGENT) < 32u)
      __builtin_amdgcn_s_sleep(1);
  }
  __syncthreads();

  u32 pv = __hip_atomic_load(xccbuf + bg + 8 * (lane & 31), __ATOMIC_RELAXED, SCOPE_AGENT);
  const bool fast = (__ballot(pv == xcc) == ~0ull);

  run_steps(hhi, hlo, io, Whi, Wlo, red, flg + bg * 128, b0, c0, cg, wave, mn, q, om, on,
            lane, !fast);
}

// ---------------- host ----------------
extern "C" void kernel_launch(void* const* d_in, const int* in_sizes, int n_in, void* d_out,
                              int out_size, void* d_ws, size_t ws_size, hipStream_t stream) {
  (void)in_sizes; (void)n_in; (void)out_size; (void)ws_size;
  const float* x    = (const float*)d_in[0];
  const float* W_in = (const float*)d_in[1];
  const float* b_in = (const float*)d_in[2];
  const float* W_hh = (const float*)d_in[3];
  const float* bias = (const float*)d_in[4];
  float* out = (float*)d_out;
  char* ws = (char*)d_ws;

  u16* win_hi = (u16*)(ws);                     // 1 MB, dead after xin_gemm
  u16* win_lo = (u16*)(ws + (1u << 20));        // 1 MB, dead after xin_gemm
  u16* whh_hi = (u16*)(ws + (2u << 20));        // 2 MB
  u16* whh_lo = (u16*)(ws + (4u << 20));        // 2 MB
  float* bsum = (float*)(ws + (6u << 20));      // 4 KB
  u16* hhi    = (u16*)(ws);                     // aliases win_hi: 8 bufs x 64x1024 u16
  u16* hlo    = (u16*)(ws + (1u << 20));        // aliases win_lo
  u32* cnt    = (u32*)(ws + (6u << 20) + 65536);           // 8 x 256B counters
  u32* xcc    = (u32*)(ws + (6u << 20) + 65536 + 4096);    // 256 u32
  u32* flg    = (u32*)(ws + (6u << 20) + 65536 + 8192);    // flags[8][128], 512B/bg

  split_arr<<<dim3(524288 / 256), dim3(256), 0, stream>>>(W_in, win_hi, win_lo, 524288);
  split_arr<<<dim3(1048576 / 256), dim3(256), 0, stream>>>(W_hh, whh_hi, whh_lo, 1048576);
  bias_init<<<dim3(8), dim3(256), 0, stream>>>(b_in, bias, bsum, cnt, flg);

  xin_gemm<<<dim3(16, 512), dim3(256), 0, stream>>>(x, win_hi, win_lo, bsum, out);

  static const unsigned kSmem = 148992;  // 2*66048 + 16896
  (void)hipFuncSetAttribute((const void*)rnn_steps, hipFuncAttributeMaxDynamicSharedMemorySize,
                            (int)kSmem);
  void* args[8];
  args[0] = (void*)&whh_hi;
  args[1] = (void*)&whh_lo;
  args[2] = (void*)&hhi;
  args[3] = (void*)&hlo;
  args[4] = (void*)&cnt;
  args[5] = (void*)&xcc;
  args[6] = (void*)&flg;
  args[7] = (void*)&out;
  (void)hipLaunchCooperativeKernel((const void*)rnn_steps, dim3(256), dim3(256, 1, 1), args,
                                   kSmem, stream);
}

// Round 10
// 1992.396 us; speedup vs baseline: 1.5711x; 1.5711x over previous
//
#include <hip/hip_runtime.h>
#include <cstdint>
#include <cstddef>

typedef unsigned short u16;
typedef unsigned int u32;
typedef unsigned long long u64;
typedef __attribute__((ext_vector_type(8))) short short8;   // 8 x bf16
typedef __attribute__((ext_vector_type(4))) float f32x4;

#define MFMA16(a, b, c) __builtin_amdgcn_mfma_f32_16x16x32_bf16((a), (b), (c), 0, 0, 0)
#define SCOPE_AGENT __HIP_MEMORY_SCOPE_AGENT

// B=64, T=512, D=512, H=1024.
// R10 = R6 verbatim (session best: 1977us total, rnn_steps ~2050us). Flag-gated
// XCD-local exchange: per-WG monotonic flags published AFTER a full store drain
// (__syncthreads vmcnt(0)); consumers sc0-poll the 128B flag block then load the
// A-slice once (sentinel backstop). R7/R8/R9 each tried to remove the store-ack
// leg (plain stores / per-wave flags / eager publish) and ALL regressed 35-48%:
// gfx950 L2 writes through to MALL structurally (WRITE_SIZE invariant), and
// ack-before-flag staggers consumers behind settled data (publish-early causes a
// thundering-herd L2 burst). This structure is the measured local optimum.

static __device__ __forceinline__ u16 f2bf_rne(float f) {
  uint32_t u = __float_as_uint(f);
  u += 0x7FFFu + ((u >> 16) & 1u);
  return (u16)(u >> 16);
}
static __device__ __forceinline__ float bf2f(u16 h) {
  return __uint_as_float((uint32_t)h << 16);
}
// sentinel: 0xFFFFFFFF = two bf16 NaNs; tanh output / its bf16 remainder are always
// finite -> never NaN -> sentinel unambiguous. Each u32 is one producer-thread store.
static __device__ __forceinline__ bool fresh2(u64 d) {
  return ((u32)d != 0xFFFFFFFFu) && ((u32)(d >> 32) != 0xFFFFFFFFu);
}

// ---------------- prep ----------------
__global__ void split_arr(const float* __restrict__ src, u16* __restrict__ hi,
                          u16* __restrict__ lo, int n) {
  int i = blockIdx.x * blockDim.x + threadIdx.x;
  if (i >= n) return;
  float f = src[i];
  u16 h = f2bf_rne(f);
  hi[i] = h;
  lo[i] = f2bf_rne(f - bf2f(h));
}

__global__ void bias_init(const float* __restrict__ a, const float* __restrict__ b,
                          float* __restrict__ o, u32* __restrict__ cnt,
                          u32* __restrict__ flg) {
  int i = blockIdx.x * blockDim.x + threadIdx.x;
  if (i < 1024) o[i] = a[i] + b[i];
  if (i < 8)  // startup-barrier counter per batch-group (256B padded)
    __hip_atomic_store(cnt + i * 64, 0u, __ATOMIC_RELAXED, SCOPE_AGENT);
  if (i < 256)  // flags[8][32] = 0 (no h published yet)
    __hip_atomic_store(flg + i, 0u, __ATOMIC_RELAXED, SCOPE_AGENT);
}

// ---------------- phase 1: xin = x @ W_in^T + bsum -> d_out (unchanged, proven) ----
__global__ __launch_bounds__(256) void xin_gemm(
    const float* __restrict__ x, const u16* __restrict__ Bh, const u16* __restrict__ Bl,
    const float* __restrict__ bsum, float* __restrict__ out) {
  __shared__ u16 Ahi[64 * 40], Alo[64 * 40], Bhi[64 * 40], Blo[64 * 40];
  const int mb = blockIdx.y * 64, nb = blockIdx.x * 64;
  const int tid = threadIdx.x, wave = tid >> 6, lane = tid & 63;
  const int mn = lane & 15, q = lane >> 4;
  const int srow = tid >> 2, scg = tid & 3;

  f32x4 acc[4] = {};
  for (int kb = 0; kb < 512; kb += 32) {
    const float* ap = x + (size_t)(mb + srow) * 512 + kb + scg * 8;
    float4 a0 = *(const float4*)ap;
    float4 a1 = *(const float4*)(ap + 4);
    float av[8] = {a0.x, a0.y, a0.z, a0.w, a1.x, a1.y, a1.z, a1.w};
    short8 vh, vl;
#pragma unroll
    for (int j = 0; j < 8; ++j) {
      u16 h = f2bf_rne(av[j]);
      vh[j] = (short)h;
      vl[j] = (short)f2bf_rne(av[j] - bf2f(h));
    }
    short8 wh = *(const short8*)(Bh + (size_t)(nb + srow) * 512 + kb + scg * 8);
    short8 wl = *(const short8*)(Bl + (size_t)(nb + srow) * 512 + kb + scg * 8);

    __syncthreads();
    *(short8*)&Ahi[srow * 40 + scg * 8] = vh;
    *(short8*)&Alo[srow * 40 + scg * 8] = vl;
    *(short8*)&Bhi[srow * 40 + scg * 8] = wh;
    *(short8*)&Blo[srow * 40 + scg * 8] = wl;
    __syncthreads();

    short8 ah = *(const short8*)&Ahi[(wave * 16 + mn) * 40 + q * 8];
    short8 al = *(const short8*)&Alo[(wave * 16 + mn) * 40 + q * 8];
#pragma unroll
    for (int nt = 0; nt < 4; ++nt) {
      short8 bh8 = *(const short8*)&Bhi[(nt * 16 + mn) * 40 + q * 8];
      short8 bl8 = *(const short8*)&Blo[(nt * 16 + mn) * 40 + q * 8];
      acc[nt] = MFMA16(ah, bh8, acc[nt]);
      acc[nt] = MFMA16(al, bh8, acc[nt]);
      acc[nt] = MFMA16(ah, bl8, acc[nt]);
    }
  }
#pragma unroll
  for (int nt = 0; nt < 4; ++nt)
#pragma unroll
    for (int r = 0; r < 4; ++r) {
      int row = mb + wave * 16 + q * 4 + r;
      int col = nb + nt * 16 + mn;
      out[(size_t)row * 1024 + col] = acc[nt][r] + bsum[col];
    }
}

// ---------------- phase 2 step loop ----------------
// Per step t: [poll 32 flags (128B) until all >= t] [issue 8 A loads, sentinel-check,
// rare retry] [xin prefetch] [per-chunk MFMA] [LDS reduce, 1 sync] [reset buf[(t+2)&3]]
// [cross-wave sum, tanh] [h store buf[(t+1)&3]] [sync; tid0: flag := t+1] [io store].
// Monotonic flags -> no flag ABA; data sentinel gate + bounded-spin escalation to
// agent scope -> correctness & termination never rest on topology assumptions.
static __device__ __forceinline__ void run_steps(
    u16* hhi, u16* hlo, float* __restrict__ io, const u16* Whi, const u16* Wlo,
    float* red, const u32* myflags, u32* myflag, int b0, int c0, int wave, int mn,
    int q, int om, int on, int tid, int lane, bool esc) {
  const int kbase = wave * 256;
  u16* aplane = (mn < 8) ? hhi : hlo;  // A rows 0-7 = hi, 8-15 = lo
  const size_t abase = (size_t)(b0 + (mn & 7)) * 1024 + kbase + q * 8;
  const size_t iobase = (size_t)(b0 + om) * 512 * 1024 + (c0 + on);
  const size_t hword = (size_t)(b0 + om) * 1024 + (c0 + on);
  const u32* fp = myflags + (lane & 31);  // lanes 32-63 mirror 0-31

  // W frags (compiler may keep in VGPR or re-read LDS; both fine)
  short8 bhf[8][2], blf[8][2];
#pragma unroll
  for (int kt = 0; kt < 8; ++kt) {
    const int k = kbase + kt * 32 + q * 8;
#pragma unroll
    for (int nt = 0; nt < 2; ++nt) {
      bhf[kt][nt] = *(const short8*)&Whi[(nt * 16 + mn) * 1032 + k];
      blf[kt][nt] = *(const short8*)&Wlo[(nt * 16 + mn) * 1032 + k];
    }
  }

  float xv = io[iobase];  // xin(0)
  {                       // t = 0: h0 == 0 -> h1 = tanh(xin0), no GEMM
    float xn = io[iobase + 1024];  // xin(1)
    float o = tanhf(xv);
    u16 hh = f2bf_rne(o);
    __hip_atomic_store(hhi + (1u << 16) + hword, hh, __ATOMIC_RELAXED, SCOPE_AGENT);
    __hip_atomic_store(hlo + (1u << 16) + hword, f2bf_rne(o - bf2f(hh)), __ATOMIC_RELAXED,
                       SCOPE_AGENT);
    __syncthreads();          // all 256 h(1) stores drained before flag
    if (tid == 0)
      __hip_atomic_store(myflag, 1u, __ATOMIC_RELAXED, SCOPE_AGENT);
    io[iobase] = o;
    xv = xn;
  }

  for (int t = 1; t < 512; ++t) {
    // ---- flag gate: wait until all 32 producers have published h(t) ----
    {
      int rounds = 0;
      for (;;) {
        u32 f;
        if (!esc)
          asm volatile("global_load_dword %0, %1, off sc0" : "=v"(f) : "v"(fp));
        else
          f = __hip_atomic_load(fp, __ATOMIC_RELAXED, SCOPE_AGENT);
        asm volatile("s_waitcnt vmcnt(0)" ::: "memory");
        __builtin_amdgcn_sched_barrier(0);
        if (__ballot(f >= (u32)t) == ~0ull) break;
        if (!esc && ++rounds >= 256) esc = true;  // sticky, proven-visible pair
      }
    }

    // ---- A-slice load; sentinel gate (rare retries) ----
    const u16* pAh = hhi + ((size_t)(t & 3) << 16);
    const u16* pAl = hlo + ((size_t)(t & 3) << 16);
    const u16* pA = ((mn < 8) ? pAh : pAl) + abase;
    int4 v[8];
#pragma unroll
    for (int kt = 0; kt < 8; ++kt) {
      if (!esc) {
        asm volatile("global_load_dwordx4 %0, %1, off sc0" : "=v"(v[kt]) : "v"(pA + kt * 32));
      } else {
        u64 a = __hip_atomic_load((const u64*)(pA + kt * 32), __ATOMIC_RELAXED, SCOPE_AGENT);
        u64 b = __hip_atomic_load((const u64*)(pA + kt * 32) + 1, __ATOMIC_RELAXED,
                                  SCOPE_AGENT);
        v[kt].x = (int)(u32)a; v[kt].y = (int)(u32)(a >> 32);
        v[kt].z = (int)(u32)b; v[kt].w = (int)(u32)(b >> 32);
      }
    }
    asm volatile("s_waitcnt vmcnt(0)" ::: "memory");
    __builtin_amdgcn_sched_barrier(0);
    u32 sm = 0;
#pragma unroll
    for (int kt = 0; kt < 8; ++kt) {
      u32 s = 0;
#pragma unroll
      for (int j = 0; j < 4; ++j) {
        u32 x = ((u32*)&v[kt])[j];
        s |= (u32)((x >> 16) == 0xFFFFu) | (u32)((x & 0xFFFFu) == 0xFFFFu);
      }
      sm |= s << kt;
    }
    {
      int spins = 0;
      while (__builtin_expect(sm != 0, 0)) {
        if (!esc && ++spins >= 256) esc = true;
#pragma unroll
        for (int kt = 0; kt < 8; ++kt) {
          if (!(sm & (1u << kt))) continue;
          if (!esc) {
            asm volatile("global_load_dwordx4 %0, %1, off sc0"
                         : "=v"(v[kt]) : "v"(pA + kt * 32));
          } else {
            u64 a = __hip_atomic_load((const u64*)(pA + kt * 32), __ATOMIC_RELAXED,
                                      SCOPE_AGENT);
            u64 b = __hip_atomic_load((const u64*)(pA + kt * 32) + 1, __ATOMIC_RELAXED,
                                      SCOPE_AGENT);
            v[kt].x = (int)(u32)a; v[kt].y = (int)(u32)(a >> 32);
            v[kt].z = (int)(u32)b; v[kt].w = (int)(u32)(b >> 32);
          }
        }
        asm volatile("s_waitcnt vmcnt(0)" ::: "memory");
        __builtin_amdgcn_sched_barrier(0);
        sm = 0;
#pragma unroll
        for (int kt = 0; kt < 8; ++kt) {
          u32 s = 0;
#pragma unroll
          for (int j = 0; j < 4; ++j) {
            u32 x = ((u32*)&v[kt])[j];
            s |= (u32)((x >> 16) == 0xFFFFu) | (u32)((x & 0xFFFFu) == 0xFFFFu);
          }
          sm |= s << kt;
        }
      }
    }

    float xn = 0.f;
    if (t < 511) xn = io[iobase + (size_t)(t + 1) * 1024];

    f32x4 acc[2] = {};
#pragma unroll
    for (int kt = 0; kt < 8; ++kt) {
      short8 a = *(short8*)&v[kt];
#pragma unroll
      for (int nt = 0; nt < 2; ++nt) {
        acc[nt] = MFMA16(a, bhf[kt][nt], acc[nt]);  // rows 0-7: hi*Whi, 8-15: lo*Whi
        acc[nt] = MFMA16(a, blf[kt][nt], acc[nt]);  // rows 0-7: hi*Wlo, 8-15: lo*Wlo
      }
    }

    // ---- cross-wave K-reduction (double-buffered red, 1 syncthreads) ----
    float* rp = red + (t & 1) * 2112;
#pragma unroll
    for (int nt = 0; nt < 2; ++nt)
#pragma unroll
      for (int r = 0; r < 4; ++r)
        rp[wave * 528 + (q * 4 + r) * 33 + nt * 16 + mn] = acc[nt][r];
    __syncthreads();

    // reset buf[(t+2)&3] now (old content h(t-2) provably fully consumed);
    // completion overlaps the sum+tanh below, drained before the flag publish.
    if (t < 510) {
      const size_t roff = ((size_t)((t + 2) & 3) << 16) + hword;
      __hip_atomic_store(hhi + roff, (u16)0xFFFFu, __ATOMIC_RELAXED, SCOPE_AGENT);
      __hip_atomic_store(hlo + roff, (u16)0xFFFFu, __ATOMIC_RELAXED, SCOPE_AGENT);
    }

    float s0 = 0.f;
#pragma unroll
    for (int w = 0; w < 4; ++w)
      s0 += rp[w * 528 + om * 33 + on] + rp[w * 528 + (om + 8) * 33 + on];
    float o = tanhf(s0 + xv);

    if (t < 511) {
      u16 hh = f2bf_rne(o);
      const size_t doff = ((size_t)((t + 1) & 3) << 16) + hword;
      __hip_atomic_store(hhi + doff, hh, __ATOMIC_RELAXED, SCOPE_AGENT);
      __hip_atomic_store(hlo + doff, f2bf_rne(o - bf2f(hh)), __ATOMIC_RELAXED, SCOPE_AGENT);
      __syncthreads();        // all 256 h(t+1) stores (and resets) drained before flag
      if (tid == 0)
        __hip_atomic_store(myflag, (u32)(t + 1), __ATOMIC_RELAXED, SCOPE_AGENT);
    }
    io[iobase + (size_t)t * 1024] = o;
    xv = xn;
  }
}

// ---------------- phase 2 kernel ----------------
// grid (256): wgid&7 = bg (8 batches), wgid>>3 = cg (32-col tile). Round-robin
// dispatch puts each bg's 32 WGs on one XCD (verified via hwreg XCC_ID; any
// mis-read is safe: false-negative -> agent path; false-positive -> bounded-spin
// escalation). h as two bf16 planes [4 bufs][64][1024]; buf[t&3] = h_t.
__global__ __launch_bounds__(256, 1) void rnn_steps(
    const u16* __restrict__ Wh, const u16* __restrict__ Wl, u16* hhi, u16* hlo,
    u32* cnt, u32* xccbuf, u32* flg, float* __restrict__ io) {
  extern __shared__ __align__(16) char smem[];
  u16* Whi = (u16*)smem;                 // [32][1032]  66048 B
  u16* Wlo = (u16*)(smem + 66048);       // [32][1032]  66048 B
  float* red = (float*)(smem + 132096);  // [2][4][16][33] 16896 B

  const int tid = threadIdx.x, wave = tid >> 6, lane = tid & 63;
  const int mn = lane & 15, q = lane >> 4;
  const int wgid = blockIdx.x;
  const int bg = wgid & 7, cg = wgid >> 3;
  const int c0 = cg * 32, b0 = bg * 8;
  u32* mycnt = cnt + bg * 64;

  // persistent W tile: 32 cols x 1024, hi+lo
  for (int it = tid; it < 32 * 128; it += 256) {
    int r = it >> 7, c = it & 127;
    *(short8*)&Whi[r * 1032 + c * 8] = *(const short8*)(Wh + (size_t)(c0 + r) * 1024 + c * 8);
    *(short8*)&Wlo[r * 1032 + c * 8] = *(const short8*)(Wl + (size_t)(c0 + r) * 1024 + c * 8);
  }

  // output ownership: 256 threads -> 8 batches x 32 cols, 1 col/thread
  const int om = tid >> 5, on = tid & 31;
  const size_t hword = (size_t)(b0 + om) * 1024 + (c0 + on);

  // sentinel-prefill my word in ALL 4 buffers (agent scope: MALL-visible on any path;
  // t=0's buf1 data store is ordered after via the pre-barrier vmcnt drain)
#pragma unroll
  for (int bb = 0; bb < 4; ++bb) {
    __hip_atomic_store(hhi + ((size_t)bb << 16) + hword, (u16)0xFFFFu, __ATOMIC_RELAXED,
                       SCOPE_AGENT);
    __hip_atomic_store(hlo + ((size_t)bb << 16) + hword, (u16)0xFFFFu, __ATOMIC_RELAXED,
                       SCOPE_AGENT);
  }

  // publish my XCD id (numeric hwreg 20 = XCC_ID, low 4 bits); per-bg startup
  // barrier; then verify bg co-residency.
  u32 xcc;
  asm volatile("s_getreg_b32 %0, hwreg(20, 0, 4)" : "=s"(xcc));
  if (tid == 0)
    __hip_atomic_store(xccbuf + wgid, xcc, __ATOMIC_RELAXED, SCOPE_AGENT);
  asm volatile("s_waitcnt vmcnt(0)" ::: "memory");
  __syncthreads();
  if (tid == 0) {
    __hip_atomic_fetch_add(mycnt, 1u, __ATOMIC_RELAXED, SCOPE_AGENT);
    while (__hip_atomic_load(mycnt, __ATOMIC_RELAXED, SCOPE_AGENT) < 32u)
      __builtin_amdgcn_s_sleep(1);
  }
  __syncthreads();

  u32 pv = __hip_atomic_load(xccbuf + bg + 8 * (lane & 31), __ATOMIC_RELAXED, SCOPE_AGENT);
  const bool fast = (__ballot(pv == xcc) == ~0ull);

  run_steps(hhi, hlo, io, Whi, Wlo, red, flg + bg * 32, flg + bg * 32 + cg, b0, c0,
            wave, mn, q, om, on, tid, lane, !fast);
}

// ---------------- host ----------------
extern "C" void kernel_launch(void* const* d_in, const int* in_sizes, int n_in, void* d_out,
                              int out_size, void* d_ws, size_t ws_size, hipStream_t stream) {
  (void)in_sizes; (void)n_in; (void)out_size; (void)ws_size;
  const float* x    = (const float*)d_in[0];
  const float* W_in = (const float*)d_in[1];
  const float* b_in = (const float*)d_in[2];
  const float* W_hh = (const float*)d_in[3];
  const float* bias = (const float*)d_in[4];
  float* out = (float*)d_out;
  char* ws = (char*)d_ws;

  u16* win_hi = (u16*)(ws);
  u16* win_lo = (u16*)(ws + (1u << 20));
  u16* whh_hi = (u16*)(ws + (2u << 20));
  u16* whh_lo = (u16*)(ws + (4u << 20));
  float* bsum = (float*)(ws + (6u << 20));
  u16* hhi    = (u16*)(ws + (6u << 20) + 65536);                // 4 x 64x1024 u16 = 512 KB
  u16* hlo    = (u16*)(ws + (6u << 20) + 65536 + (512u << 10)); // 512 KB
  u32* cnt    = (u32*)(ws + (6u << 20) + 65536 + (1u << 20));   // 8 x 256B counters
  u32* xcc    = (u32*)(ws + (6u << 20) + 65536 + (1u << 20) + 2048);  // 256 u32
  u32* flg    = (u32*)(ws + (6u << 20) + 65536 + (1u << 20) + 4096);  // flags[8][32]

  split_arr<<<dim3(524288 / 256), dim3(256), 0, stream>>>(W_in, win_hi, win_lo, 524288);
  split_arr<<<dim3(1048576 / 256), dim3(256), 0, stream>>>(W_hh, whh_hi, whh_lo, 1048576);
  bias_init<<<dim3(8), dim3(256), 0, stream>>>(b_in, bias, bsum, cnt, flg);

  xin_gemm<<<dim3(16, 512), dim3(256), 0, stream>>>(x, win_hi, win_lo, bsum, out);

  static const unsigned kSmem = 148992;  // 2*66048 + 16896
  (void)hipFuncSetAttribute((const void*)rnn_steps, hipFuncAttributeMaxDynamicSharedMemorySize,
                            (int)kSmem);
  void* args[8];
  args[0] = (void*)&whh_hi;
  args[1] = (void*)&whh_lo;
  args[2] = (void*)&hhi;
  args[3] = (void*)&hlo;
  args[4] = (void*)&cnt;
  args[5] = (void*)&xcc;
  args[6] = (void*)&flg;
  args[7] = (void*)&out;
  (void)hipLaunchCooperativeKernel((const void*)rnn_steps, dim3(256), dim3(256, 1, 1), args,
                                   kSmem, stream);
}

// Round 11
// 1964.896 us; speedup vs baseline: 1.5931x; 1.0140x over previous
//
#include <hip/hip_runtime.h>
#include <cstdint>
#include <cstddef>

typedef unsigned short u16;
typedef unsigned int u32;
typedef unsigned long long u64;
typedef __attribute__((ext_vector_type(8))) short short8;   // 8 x bf16
typedef __attribute__((ext_vector_type(4))) float f32x4;

#define MFMA16(a, b, c) __builtin_amdgcn_mfma_f32_16x16x32_bf16((a), (b), (c), 0, 0, 0)
#define SCOPE_AGENT __HIP_MEMORY_SCOPE_AGENT

// B=64, T=512, D=512, H=1024.
// R11 = R6/R10 (session best, 1977/1992us) + ONE change: narrow per-wave flag gate.
// Wave w polls only the 8 flags of the producer cgs it consumes (features
// [256w,256w+256) <- cgs 8w..8w+7) instead of all 32. Early waves start A-loads +
// MFMA while the slowest producer drains; the max-over-32 alignment moves to the
// reduce __syncthreads where it overlaps compute. Safety (2-hop induction):
// flag(X)>=t => X's 4 waves passed gate(t-1), windows union = all 32 cgs => all
// cgs >= t-1 => all step-(t-2) reads done => reset of buf[(t+2)&3] (h(t-2)) safe.
// Everything else verbatim R6: per-WG flag published after full __syncthreads
// vmcnt drain (ack-before-flag is load-bearing: R9's eager publish cost +48%),
// agent h/flag stores (WRITE_SIZE invariant across store flavors: L2 writes
// through to MALL structurally), sc0 polls + sentinel backstop + sticky
// bounded-spin escalation to agent scope (hang-proof on any topology).

static __device__ __forceinline__ u16 f2bf_rne(float f) {
  uint32_t u = __float_as_uint(f);
  u += 0x7FFFu + ((u >> 16) & 1u);
  return (u16)(u >> 16);
}
static __device__ __forceinline__ float bf2f(u16 h) {
  return __uint_as_float((uint32_t)h << 16);
}

// ---------------- prep ----------------
__global__ void split_arr(const float* __restrict__ src, u16* __restrict__ hi,
                          u16* __restrict__ lo, int n) {
  int i = blockIdx.x * blockDim.x + threadIdx.x;
  if (i >= n) return;
  float f = src[i];
  u16 h = f2bf_rne(f);
  hi[i] = h;
  lo[i] = f2bf_rne(f - bf2f(h));
}

__global__ void bias_init(const float* __restrict__ a, const float* __restrict__ b,
                          float* __restrict__ o, u32* __restrict__ cnt,
                          u32* __restrict__ flg) {
  int i = blockIdx.x * blockDim.x + threadIdx.x;
  if (i < 1024) o[i] = a[i] + b[i];
  if (i < 8)  // startup-barrier counter per batch-group (256B padded)
    __hip_atomic_store(cnt + i * 64, 0u, __ATOMIC_RELAXED, SCOPE_AGENT);
  if (i < 256)  // flags[8][32] = 0 (no h published yet)
    __hip_atomic_store(flg + i, 0u, __ATOMIC_RELAXED, SCOPE_AGENT);
}

// ---------------- phase 1: xin = x @ W_in^T + bsum -> d_out (unchanged, proven) ----
__global__ __launch_bounds__(256) void xin_gemm(
    const float* __restrict__ x, const u16* __restrict__ Bh, const u16* __restrict__ Bl,
    const float* __restrict__ bsum, float* __restrict__ out) {
  __shared__ u16 Ahi[64 * 40], Alo[64 * 40], Bhi[64 * 40], Blo[64 * 40];
  const int mb = blockIdx.y * 64, nb = blockIdx.x * 64;
  const int tid = threadIdx.x, wave = tid >> 6, lane = tid & 63;
  const int mn = lane & 15, q = lane >> 4;
  const int srow = tid >> 2, scg = tid & 3;

  f32x4 acc[4] = {};
  for (int kb = 0; kb < 512; kb += 32) {
    const float* ap = x + (size_t)(mb + srow) * 512 + kb + scg * 8;
    float4 a0 = *(const float4*)ap;
    float4 a1 = *(const float4*)(ap + 4);
    float av[8] = {a0.x, a0.y, a0.z, a0.w, a1.x, a1.y, a1.z, a1.w};
    short8 vh, vl;
#pragma unroll
    for (int j = 0; j < 8; ++j) {
      u16 h = f2bf_rne(av[j]);
      vh[j] = (short)h;
      vl[j] = (short)f2bf_rne(av[j] - bf2f(h));
    }
    short8 wh = *(const short8*)(Bh + (size_t)(nb + srow) * 512 + kb + scg * 8);
    short8 wl = *(const short8*)(Bl + (size_t)(nb + srow) * 512 + kb + scg * 8);

    __syncthreads();
    *(short8*)&Ahi[srow * 40 + scg * 8] = vh;
    *(short8*)&Alo[srow * 40 + scg * 8] = vl;
    *(short8*)&Bhi[srow * 40 + scg * 8] = wh;
    *(short8*)&Blo[srow * 40 + scg * 8] = wl;
    __syncthreads();

    short8 ah = *(const short8*)&Ahi[(wave * 16 + mn) * 40 + q * 8];
    short8 al = *(const short8*)&Alo[(wave * 16 + mn) * 40 + q * 8];
#pragma unroll
    for (int nt = 0; nt < 4; ++nt) {
      short8 bh8 = *(const short8*)&Bhi[(nt * 16 + mn) * 40 + q * 8];
      short8 bl8 = *(const short8*)&Blo[(nt * 16 + mn) * 40 + q * 8];
      acc[nt] = MFMA16(ah, bh8, acc[nt]);
      acc[nt] = MFMA16(al, bh8, acc[nt]);
      acc[nt] = MFMA16(ah, bl8, acc[nt]);
    }
  }
#pragma unroll
  for (int nt = 0; nt < 4; ++nt)
#pragma unroll
    for (int r = 0; r < 4; ++r) {
      int row = mb + wave * 16 + q * 4 + r;
      int col = nb + nt * 16 + mn;
      out[(size_t)row * 1024 + col] = acc[nt][r] + bsum[col];
    }
}

// ---------------- phase 2 step loop ----------------
// Per step t: [NARROW gate: wave w polls its 8 producer flags until >= t]
// [issue 8 A loads, sentinel-check, rare retry] [xin prefetch] [per-chunk MFMA]
// [LDS reduce, 1 sync (max-of-32 alignment lands here, overlapping compute)]
// [reset buf[(t+2)&3]] [cross-wave sum, tanh] [h store buf[(t+1)&3]]
// [sync; tid0: flag := t+1] [io store].
static __device__ __forceinline__ void run_steps(
    u16* hhi, u16* hlo, float* __restrict__ io, const u16* Whi, const u16* Wlo,
    float* red, const u32* myflags, u32* myflag, int b0, int c0, int wave, int mn,
    int q, int om, int on, int tid, int lane, bool esc) {
  const int kbase = wave * 256;
  const size_t abase = (size_t)(b0 + (mn & 7)) * 1024 + kbase + q * 8;
  const size_t iobase = (size_t)(b0 + om) * 512 * 1024 + (c0 + on);
  const size_t hword = (size_t)(b0 + om) * 1024 + (c0 + on);
  // NARROW gate: wave w consumes features [256w,256w+256) from cgs 8w..8w+7;
  // all 64 lanes load one of those 8 flags (8x replicated), ballot over all.
  const u32* fp = myflags + wave * 8 + (lane & 7);

  // W frags (compiler may keep in VGPR or re-read LDS; both fine)
  short8 bhf[8][2], blf[8][2];
#pragma unroll
  for (int kt = 0; kt < 8; ++kt) {
    const int k = kbase + kt * 32 + q * 8;
#pragma unroll
    for (int nt = 0; nt < 2; ++nt) {
      bhf[kt][nt] = *(const short8*)&Whi[(nt * 16 + mn) * 1032 + k];
      blf[kt][nt] = *(const short8*)&Wlo[(nt * 16 + mn) * 1032 + k];
    }
  }

  float xv = io[iobase];  // xin(0)
  {                       // t = 0: h0 == 0 -> h1 = tanh(xin0), no GEMM
    float xn = io[iobase + 1024];  // xin(1)
    float o = tanhf(xv);
    u16 hh = f2bf_rne(o);
    __hip_atomic_store(hhi + (1u << 16) + hword, hh, __ATOMIC_RELAXED, SCOPE_AGENT);
    __hip_atomic_store(hlo + (1u << 16) + hword, f2bf_rne(o - bf2f(hh)), __ATOMIC_RELAXED,
                       SCOPE_AGENT);
    __syncthreads();          // all 256 h(1) stores drained before flag
    if (tid == 0)
      __hip_atomic_store(myflag, 1u, __ATOMIC_RELAXED, SCOPE_AGENT);
    io[iobase] = o;
    xv = xn;
  }

  for (int t = 1; t < 512; ++t) {
    // ---- narrow flag gate: my wave's 8 producers have published h(t) ----
    {
      int rounds = 0;
      for (;;) {
        u32 f;
        if (!esc)
          asm volatile("global_load_dword %0, %1, off sc0" : "=v"(f) : "v"(fp));
        else
          f = __hip_atomic_load(fp, __ATOMIC_RELAXED, SCOPE_AGENT);
        asm volatile("s_waitcnt vmcnt(0)" ::: "memory");
        __builtin_amdgcn_sched_barrier(0);
        if (__ballot(f >= (u32)t) == ~0ull) break;
        if (!esc && ++rounds >= 256) esc = true;  // sticky, proven-visible pair
      }
    }

    // ---- A-slice load; sentinel gate (rare retries) ----
    const u16* pAh = hhi + ((size_t)(t & 3) << 16);
    const u16* pAl = hlo + ((size_t)(t & 3) << 16);
    const u16* pA = ((mn < 8) ? pAh : pAl) + abase;
    int4 v[8];
#pragma unroll
    for (int kt = 0; kt < 8; ++kt) {
      if (!esc) {
        asm volatile("global_load_dwordx4 %0, %1, off sc0" : "=v"(v[kt]) : "v"(pA + kt * 32));
      } else {
        u64 a = __hip_atomic_load((const u64*)(pA + kt * 32), __ATOMIC_RELAXED, SCOPE_AGENT);
        u64 b = __hip_atomic_load((const u64*)(pA + kt * 32) + 1, __ATOMIC_RELAXED,
                                  SCOPE_AGENT);
        v[kt].x = (int)(u32)a; v[kt].y = (int)(u32)(a >> 32);
        v[kt].z = (int)(u32)b; v[kt].w = (int)(u32)(b >> 32);
      }
    }
    asm volatile("s_waitcnt vmcnt(0)" ::: "memory");
    __builtin_amdgcn_sched_barrier(0);
    u32 sm = 0;
#pragma unroll
    for (int kt = 0; kt < 8; ++kt) {
      u32 s = 0;
#pragma unroll
      for (int j = 0; j < 4; ++j) {
        u32 x = ((u32*)&v[kt])[j];
        s |= (u32)((x >> 16) == 0xFFFFu) | (u32)((x & 0xFFFFu) == 0xFFFFu);
      }
      sm |= s << kt;
    }
    {
      int spins = 0;
      while (__builtin_expect(sm != 0, 0)) {
        if (!esc && ++spins >= 256) esc = true;
#pragma unroll
        for (int kt = 0; kt < 8; ++kt) {
          if (!(sm & (1u << kt))) continue;
          if (!esc) {
            asm volatile("global_load_dwordx4 %0, %1, off sc0"
                         : "=v"(v[kt]) : "v"(pA + kt * 32));
          } else {
            u64 a = __hip_atomic_load((const u64*)(pA + kt * 32), __ATOMIC_RELAXED,
                                      SCOPE_AGENT);
            u64 b = __hip_atomic_load((const u64*)(pA + kt * 32) + 1, __ATOMIC_RELAXED,
                                      SCOPE_AGENT);
            v[kt].x = (int)(u32)a; v[kt].y = (int)(u32)(a >> 32);
            v[kt].z = (int)(u32)b; v[kt].w = (int)(u32)(b >> 32);
          }
        }
        asm volatile("s_waitcnt vmcnt(0)" ::: "memory");
        __builtin_amdgcn_sched_barrier(0);
        sm = 0;
#pragma unroll
        for (int kt = 0; kt < 8; ++kt) {
          u32 s = 0;
#pragma unroll
          for (int j = 0; j < 4; ++j) {
            u32 x = ((u32*)&v[kt])[j];
            s |= (u32)((x >> 16) == 0xFFFFu) | (u32)((x & 0xFFFFu) == 0xFFFFu);
          }
          sm |= s << kt;
        }
      }
    }

    float xn = 0.f;
    if (t < 511) xn = io[iobase + (size_t)(t + 1) * 1024];

    f32x4 acc[2] = {};
#pragma unroll
    for (int kt = 0; kt < 8; ++kt) {
      short8 a = *(short8*)&v[kt];
#pragma unroll
      for (int nt = 0; nt < 2; ++nt) {
        acc[nt] = MFMA16(a, bhf[kt][nt], acc[nt]);  // rows 0-7: hi*Whi, 8-15: lo*Whi
        acc[nt] = MFMA16(a, blf[kt][nt], acc[nt]);  // rows 0-7: hi*Wlo, 8-15: lo*Wlo
      }
    }

    // ---- cross-wave K-reduction (double-buffered red, 1 syncthreads) ----
    float* rp = red + (t & 1) * 2112;
#pragma unroll
    for (int nt = 0; nt < 2; ++nt)
#pragma unroll
      for (int r = 0; r < 4; ++r)
        rp[wave * 528 + (q * 4 + r) * 33 + nt * 16 + mn] = acc[nt][r];
    __syncthreads();

    // reset buf[(t+2)&3]: safe — my gate saw a producer >= t, which (2-hop) implies
    // every cg finished step t-2's reads of this buffer. Drained before flag below.
    if (t < 510) {
      const size_t roff = ((size_t)((t + 2) & 3) << 16) + hword;
      __hip_atomic_store(hhi + roff, (u16)0xFFFFu, __ATOMIC_RELAXED, SCOPE_AGENT);
      __hip_atomic_store(hlo + roff, (u16)0xFFFFu, __ATOMIC_RELAXED, SCOPE_AGENT);
    }

    float s0 = 0.f;
#pragma unroll
    for (int w = 0; w < 4; ++w)
      s0 += rp[w * 528 + om * 33 + on] + rp[w * 528 + (om + 8) * 33 + on];
    float o = tanhf(s0 + xv);

    if (t < 511) {
      u16 hh = f2bf_rne(o);
      const size_t doff = ((size_t)((t + 1) & 3) << 16) + hword;
      __hip_atomic_store(hhi + doff, hh, __ATOMIC_RELAXED, SCOPE_AGENT);
      __hip_atomic_store(hlo + doff, f2bf_rne(o - bf2f(hh)), __ATOMIC_RELAXED, SCOPE_AGENT);
      __syncthreads();        // all 256 h(t+1) stores (and resets) drained before flag
      if (tid == 0)
        __hip_atomic_store(myflag, (u32)(t + 1), __ATOMIC_RELAXED, SCOPE_AGENT);
    }
    io[iobase + (size_t)t * 1024] = o;
    xv = xn;
  }
}

// ---------------- phase 2 kernel ----------------
// grid (256): wgid&7 = bg (8 batches), wgid>>3 = cg (32-col tile). Round-robin
// dispatch puts each bg's 32 WGs on one XCD (verified via hwreg XCC_ID; any
// mis-read is safe: false-negative -> agent path; false-positive -> bounded-spin
// escalation). h as two bf16 planes [4 bufs][64][1024]; buf[t&3] = h_t.
__global__ __launch_bounds__(256, 1) void rnn_steps(
    const u16* __restrict__ Wh, const u16* __restrict__ Wl, u16* hhi, u16* hlo,
    u32* cnt, u32* xccbuf, u32* flg, float* __restrict__ io) {
  extern __shared__ __align__(16) char smem[];
  u16* Whi = (u16*)smem;                 // [32][1032]  66048 B
  u16* Wlo = (u16*)(smem + 66048);       // [32][1032]  66048 B
  float* red = (float*)(smem + 132096);  // [2][4][16][33] 16896 B

  const int tid = threadIdx.x, wave = tid >> 6, lane = tid & 63;
  const int mn = lane & 15, q = lane >> 4;
  const int wgid = blockIdx.x;
  const int bg = wgid & 7, cg = wgid >> 3;
  const int c0 = cg * 32, b0 = bg * 8;
  u32* mycnt = cnt + bg * 64;

  // persistent W tile: 32 cols x 1024, hi+lo
  for (int it = tid; it < 32 * 128; it += 256) {
    int r = it >> 7, c = it & 127;
    *(short8*)&Whi[r * 1032 + c * 8] = *(const short8*)(Wh + (size_t)(c0 + r) * 1024 + c * 8);
    *(short8*)&Wlo[r * 1032 + c * 8] = *(const short8*)(Wl + (size_t)(c0 + r) * 1024 + c * 8);
  }

  // output ownership: 256 threads -> 8 batches x 32 cols, 1 col/thread
  const int om = tid >> 5, on = tid & 31;
  const size_t hword = (size_t)(b0 + om) * 1024 + (c0 + on);

  // sentinel-prefill my word in ALL 4 buffers (agent scope: MALL-visible on any path;
  // t=0's buf1 data store is ordered after via the pre-barrier vmcnt drain)
#pragma unroll
  for (int bb = 0; bb < 4; ++bb) {
    __hip_atomic_store(hhi + ((size_t)bb << 16) + hword, (u16)0xFFFFu, __ATOMIC_RELAXED,
                       SCOPE_AGENT);
    __hip_atomic_store(hlo + ((size_t)bb << 16) + hword, (u16)0xFFFFu, __ATOMIC_RELAXED,
                       SCOPE_AGENT);
  }

  // publish my XCD id (numeric hwreg 20 = XCC_ID, low 4 bits); per-bg startup
  // barrier; then verify bg co-residency.
  u32 xcc;
  asm volatile("s_getreg_b32 %0, hwreg(20, 0, 4)" : "=s"(xcc));
  if (tid == 0)
    __hip_atomic_store(xccbuf + wgid, xcc, __ATOMIC_RELAXED, SCOPE_AGENT);
  asm volatile("s_waitcnt vmcnt(0)" ::: "memory");
  __syncthreads();
  if (tid == 0) {
    __hip_atomic_fetch_add(mycnt, 1u, __ATOMIC_RELAXED, SCOPE_AGENT);
    while (__hip_atomic_load(mycnt, __ATOMIC_RELAXED, SCOPE_AGENT) < 32u)
      __builtin_amdgcn_s_sleep(1);
  }
  __syncthreads();

  u32 pv = __hip_atomic_load(xccbuf + bg + 8 * (lane & 31), __ATOMIC_RELAXED, SCOPE_AGENT);
  const bool fast = (__ballot(pv == xcc) == ~0ull);

  run_steps(hhi, hlo, io, Whi, Wlo, red, flg + bg * 32, flg + bg * 32 + cg, b0, c0,
            wave, mn, q, om, on, tid, lane, !fast);
}

// ---------------- host ----------------
extern "C" void kernel_launch(void* const* d_in, const int* in_sizes, int n_in, void* d_out,
                              int out_size, void* d_ws, size_t ws_size, hipStream_t stream) {
  (void)in_sizes; (void)n_in; (void)out_size; (void)ws_size;
  const float* x    = (const float*)d_in[0];
  const float* W_in = (const float*)d_in[1];
  const float* b_in = (const float*)d_in[2];
  const float* W_hh = (const float*)d_in[3];
  const float* bias = (const float*)d_in[4];
  float* out = (float*)d_out;
  char* ws = (char*)d_ws;

  u16* win_hi = (u16*)(ws);
  u16* win_lo = (u16*)(ws + (1u << 20));
  u16* whh_hi = (u16*)(ws + (2u << 20));
  u16* whh_lo = (u16*)(ws + (4u << 20));
  float* bsum = (float*)(ws + (6u << 20));
  u16* hhi    = (u16*)(ws + (6u << 20) + 65536);                // 4 x 64x1024 u16 = 512 KB
  u16* hlo    = (u16*)(ws + (6u << 20) + 65536 + (512u << 10)); // 512 KB
  u32* cnt    = (u32*)(ws + (6u << 20) + 65536 + (1u << 20));   // 8 x 256B counters
  u32* xcc    = (u32*)(ws + (6u << 20) + 65536 + (1u << 20) + 2048);  // 256 u32
  u32* flg    = (u32*)(ws + (6u << 20) + 65536 + (1u << 20) + 4096);  // flags[8][32]

  split_arr<<<dim3(524288 / 256), dim3(256), 0, stream>>>(W_in, win_hi, win_lo, 524288);
  split_arr<<<dim3(1048576 / 256), dim3(256), 0, stream>>>(W_hh, whh_hi, whh_lo, 1048576);
  bias_init<<<dim3(8), dim3(256), 0, stream>>>(b_in, bias, bsum, cnt, flg);

  xin_gemm<<<dim3(16, 512), dim3(256), 0, stream>>>(x, win_hi, win_lo, bsum, out);

  static const unsigned kSmem = 148992;  // 2*66048 + 16896
  (void)hipFuncSetAttribute((const void*)rnn_steps, hipFuncAttributeMaxDynamicSharedMemorySize,
                            (int)kSmem);
  void* args[8];
  args[0] = (void*)&whh_hi;
  args[1] = (void*)&whh_lo;
  args[2] = (void*)&hhi;
  args[3] = (void*)&hlo;
  args[4] = (void*)&cnt;
  args[5] = (void*)&xcc;
  args[6] = (void*)&flg;
  args[7] = (void*)&out;
  (void)hipLaunchCooperativeKernel((const void*)rnn_steps, dim3(256), dim3(256, 1, 1), args,
                                   kSmem, stream);
}